// Round 1
// 814.048 us; speedup vs baseline: 1.0179x; 1.0179x over previous
//
#include <hip/hip_runtime.h>

#define N_NODES 40000
#define N_EDGES 640000

typedef __attribute__((ext_vector_type(8))) short short8;
typedef __attribute__((ext_vector_type(4))) float float4v;

__device__ inline short f2bf(float f) {
  unsigned u = __float_as_uint(f);
  unsigned r = (u + 0x7FFFu + ((u >> 16) & 1u)) >> 16;
  return (short)r;
}

// ---- convert + transpose weights to bf16: Wt[c][k] = bf16(W[k][c]) ----
__global__ void prep_w(const float* __restrict__ Wm, const float* __restrict__ We,
                       const float* __restrict__ Ws, short* __restrict__ WtM,
                       short* __restrict__ WtE, short* __restrict__ WtS) {
  int i = blockIdx.x * 256 + threadIdx.x;  // 40960 total
  if (i < 16384) {
    int c = i >> 7, k = i & 127;
    WtM[c * 128 + k] = f2bf(Wm[k * 128 + c]);
  } else if (i < 32768) {
    int j = i - 16384;
    int c = j >> 7, k = j & 127;
    WtE[c * 128 + k] = f2bf(We[k * 128 + c]);
  } else {
    int j = i - 32768;
    int c = j >> 7, k = j & 127;  // c in 0..63
    WtS[c * 128 + k] = f2bf(Ws[k * 64 + c]);
  }
}

// ---- generic row-tile GEMM: out[M, NT*16] = A[M,128] @ W[128, NT*16] + bias ----
template <int NT>
__global__ __launch_bounds__(256) void gemm_rows(const float* __restrict__ A,
                                                 const short* __restrict__ Wt,
                                                 const float* __restrict__ bias,
                                                 float* __restrict__ out) {
  __shared__ short wt[NT * 16 * 136];
  for (int i = threadIdx.x; i < NT * 16 * 16; i += 256) {
    int c = i >> 4, j = i & 15;
    *(uint4*)&wt[c * 136 + j * 8] = ((const uint4*)Wt)[i];
  }
  __syncthreads();
  const int l = threadIdx.x & 63, w = threadIdx.x >> 6;
  const int lr = l & 15, q = l >> 4;
  const int row = blockIdx.x * 64 + w * 16 + lr;
  float4v acc[NT];
#pragma unroll
  for (int t = 0; t < NT; ++t) acc[t] = (float4v){0.f, 0.f, 0.f, 0.f};
  const float* ap = A + (size_t)row * 128 + q * 8;
#pragma unroll
  for (int s = 0; s < 4; ++s) {
    float4 a0 = *(const float4*)(ap + s * 32);
    float4 a1 = *(const float4*)(ap + s * 32 + 4);
    short8 af;
    af[0] = f2bf(a0.x); af[1] = f2bf(a0.y); af[2] = f2bf(a0.z); af[3] = f2bf(a0.w);
    af[4] = f2bf(a1.x); af[5] = f2bf(a1.y); af[6] = f2bf(a1.z); af[7] = f2bf(a1.w);
#pragma unroll
    for (int t = 0; t < NT; ++t) {
      short8 bf = *(const short8*)&wt[(t * 16 + lr) * 136 + s * 32 + q * 8];
      acc[t] = __builtin_amdgcn_mfma_f32_16x16x32_bf16(af, bf, acc[t], 0, 0, 0);
    }
  }
  const int orow = blockIdx.x * 64 + w * 16 + q * 4;
#pragma unroll
  for (int t = 0; t < NT; ++t) {
    int col = lr + 16 * t;
    float b = bias[col];
#pragma unroll
    for (int j = 0; j < 4; ++j)
      out[(size_t)(orow + j) * (NT * 16) + col] = acc[t][j] + b;
  }
}

// ---- fused edge kernel: le = ea@W_edge + b_edge (store), m = le + xm[src],
//      alpha[e,h] = leaky_relu(sum_c m[e,h*64+c]*att[h*64+c]) ----
__global__ __launch_bounds__(256) void edge_kernel(
    const float* __restrict__ ea, const short* __restrict__ WtE,
    const float* __restrict__ b_edge, const float* __restrict__ xm,
    const float* __restrict__ att, const int* __restrict__ src,
    float* __restrict__ le_out, float* __restrict__ alpha_out) {
  __shared__ short wt[128 * 136];
  __shared__ int sid[64];
  for (int i = threadIdx.x; i < 128 * 16; i += 256) {
    int c = i >> 4, j = i & 15;
    *(uint4*)&wt[c * 136 + j * 8] = ((const uint4*)WtE)[i];
  }
  if (threadIdx.x < 64) sid[threadIdx.x] = src[blockIdx.x * 64 + threadIdx.x];
  __syncthreads();
  const int l = threadIdx.x & 63, w = threadIdx.x >> 6;
  const int lr = l & 15, q = l >> 4;
  const int r0 = blockIdx.x * 64 + w * 16;
  float4v acc[8];
#pragma unroll
  for (int t = 0; t < 8; ++t) acc[t] = (float4v){0.f, 0.f, 0.f, 0.f};
  const float* ap = ea + (size_t)(r0 + lr) * 128 + q * 8;
#pragma unroll
  for (int s = 0; s < 4; ++s) {
    float4 a0 = *(const float4*)(ap + s * 32);
    float4 a1 = *(const float4*)(ap + s * 32 + 4);
    short8 af;
    af[0] = f2bf(a0.x); af[1] = f2bf(a0.y); af[2] = f2bf(a0.z); af[3] = f2bf(a0.w);
    af[4] = f2bf(a1.x); af[5] = f2bf(a1.y); af[6] = f2bf(a1.z); af[7] = f2bf(a1.w);
#pragma unroll
    for (int t = 0; t < 8; ++t) {
      short8 bf = *(const short8*)&wt[(t * 16 + lr) * 136 + s * 32 + q * 8];
      acc[t] = __builtin_amdgcn_mfma_f32_16x16x32_bf16(af, bf, acc[t], 0, 0, 0);
    }
  }
  const int rb = q * 4;
  int sidr[4];
#pragma unroll
  for (int j = 0; j < 4; ++j) sidr[j] = sid[w * 16 + rb + j];
  float p[8];
#pragma unroll
  for (int k = 0; k < 8; ++k) p[k] = 0.f;
#pragma unroll
  for (int t = 0; t < 8; ++t) {
    int col = lr + 16 * t;
    float b = b_edge[col];
    float av = att[col];
    int hp = (t >> 2) * 4;  // head = col>>6 = t>>2
#pragma unroll
    for (int j = 0; j < 4; ++j) {
      float lev = acc[t][j] + b;
      le_out[(size_t)(r0 + rb + j) * 128 + col] = lev;
      float mv = lev + xm[(size_t)sidr[j] * 128 + col];
      p[hp + j] += mv * av;
    }
  }
  // butterfly-reduce over the 16 lanes of each quad group
#pragma unroll
  for (int d = 1; d < 16; d <<= 1) {
#pragma unroll
    for (int k = 0; k < 8; ++k) p[k] += __shfl_xor(p[k], d);
  }
  if (lr < 8) {
    int j = lr >> 1, h = lr & 1;
    float v = p[h * 4 + j];
    alpha_out[(size_t)(r0 + rb + j) * 2 + h] = v > 0.f ? v : 0.2f * v;
  }
}

// ==================== CSR build (by destination) ====================

// rank[e] = arrival index within dst bucket; cnt[d] = degree
__global__ void hist_k(const int* __restrict__ dst, int* __restrict__ cnt,
                       int* __restrict__ rank) {
  int e = blockIdx.x * 256 + threadIdx.x;  // E exact
  rank[e] = atomicAdd(&cnt[dst[e]], 1);
}

// single-block exclusive scan of cnt[0..N) -> ofs[0..N]
__global__ __launch_bounds__(1024) void scan_k(const int* __restrict__ cnt,
                                               int* __restrict__ ofs) {
  __shared__ int tsum[1024];
  const int t = threadIdx.x;
  const int b = t * 40;                       // 1024*40 = 40960 >= 40000
  const int hi = min(b + 40, N_NODES);
  int s = 0;
  for (int i = b; i < hi; ++i) s += cnt[i];
  tsum[t] = s;
  __syncthreads();
  for (int d = 1; d < 1024; d <<= 1) {
    int v = (t >= d) ? tsum[t - d] : 0;
    __syncthreads();
    tsum[t] += v;
    __syncthreads();
  }
  int run = (t == 0) ? 0 : tsum[t - 1];       // exclusive base for this chunk
  for (int i = b; i < hi; ++i) { ofs[i] = run; run += cnt[i]; }
  if (t == 1023) ofs[N_NODES] = run;          // grand total (chunks >=1000 empty)
}

__global__ void scatter_k(const int* __restrict__ dst, const int* __restrict__ ofs,
                          const int* __restrict__ rank, int* __restrict__ eid) {
  int e = blockIdx.x * 256 + threadIdx.x;  // E exact
  eid[ofs[dst[e]] + rank[e]] = e;
}

// ==================== per-node softmax + aggregation (no atomics) ====================
// one wave per node; lane l owns channel l of both heads (cols l and 64+l).
__global__ __launch_bounds__(256) void node_agg(
    const float* __restrict__ le, const float* __restrict__ xm,
    const float* __restrict__ alp, const float* __restrict__ xs,
    const int* __restrict__ ofs, const int* __restrict__ eid,
    const int* __restrict__ src, float* __restrict__ out) {
  const int w = threadIdx.x >> 6, l = threadIdx.x & 63;
  const int n = blockIdx.x * 4 + w;  // grid 10000 -> 40000 nodes exact
  const int beg = ofs[n];
  const int deg = ofs[n + 1] - beg;
  float acc = 0.f;
  if (deg > 0) {
    // pass 1: segment max per head
    float m0 = -1e30f, m1 = -1e30f;
    for (int i = l; i < deg; i += 64) {
      int e = eid[beg + i];
      m0 = fmaxf(m0, alp[2 * e]);
      m1 = fmaxf(m1, alp[2 * e + 1]);
    }
#pragma unroll
    for (int d = 1; d < 64; d <<= 1) {
      m0 = fmaxf(m0, __shfl_xor(m0, d));
      m1 = fmaxf(m1, __shfl_xor(m1, d));
    }
    // pass 2: segment denom per head
    float s0 = 0.f, s1 = 0.f;
    for (int i = l; i < deg; i += 64) {
      int e = eid[beg + i];
      s0 += __expf(alp[2 * e] - m0);
      s1 += __expf(alp[2 * e + 1] - m1);
    }
#pragma unroll
    for (int d = 1; d < 64; d <<= 1) {
      s0 += __shfl_xor(s0, d);
      s1 += __shfl_xor(s1, d);
    }
    const float r0 = 1.f / (s0 + 1e-16f);
    const float r1 = 1.f / (s1 + 1e-16f);
    // pass 3: weighted aggregate, 64-edge chunks with register broadcast
    for (int base = 0; base < deg; base += 64) {
      int i = base + l;
      int eR = 0, sR = 0;
      float w0R = 0.f, w1R = 0.f;
      if (i < deg) {
        eR = eid[beg + i];
        sR = src[eR];
        w0R = __expf(alp[2 * eR] - m0) * r0;
        w1R = __expf(alp[2 * eR + 1] - m1) * r1;
      }
      const int c = min(64, deg - base);
      for (int j = 0; j < c; ++j) {
        int e = __shfl(eR, j);
        int s = __shfl(sR, j);
        float w0 = __shfl(w0R, j);
        float w1 = __shfl(w1R, j);
        float v0 = le[(size_t)e * 128 + l] + xm[(size_t)s * 128 + l];
        float v1 = le[(size_t)e * 128 + 64 + l] + xm[(size_t)s * 128 + 64 + l];
        acc += w0 * v0 + w1 * v1;
      }
    }
  }
  out[(size_t)n * 64 + l] = 0.5f * acc + xs[(size_t)n * 64 + l];
}

extern "C" void kernel_launch(void* const* d_in, const int* in_sizes, int n_in,
                              void* d_out, int out_size, void* d_ws, size_t ws_size,
                              hipStream_t stream) {
  const float* x      = (const float*)d_in[0];
  const float* ea     = (const float*)d_in[1];
  const float* W_msg  = (const float*)d_in[2];
  const float* b_msg  = (const float*)d_in[3];
  const float* W_edge = (const float*)d_in[4];
  const float* b_edge = (const float*)d_in[5];
  const float* W_self = (const float*)d_in[6];
  const float* b_self = (const float*)d_in[7];
  const float* att    = (const float*)d_in[8];
  const int*   eidx   = (const int*)d_in[9];
  const int* src = eidx;
  const int* dst = eidx + N_EDGES;
  float* out_p = (float*)d_out;
  float* le_p  = out_p + (size_t)N_NODES * 64;

  char* ws = (char*)d_ws;
  short* WtM  = (short*)(ws);                  // 32768 B
  short* WtE  = (short*)(ws + 32768);          // 32768 B
  short* WtS  = (short*)(ws + 65536);          // 16384 B
  float* xm   = (float*)(ws + 81920);          // N*128*4 = 20,480,000 B
  float* xs   = (float*)(ws + 20561920);       // N*64*4  = 10,240,000 B
  float* alp  = (float*)(ws + 30801920);       // E*2*4   =  5,120,000 B
  int*   cnt  = (int*)(ws + 35921920);         // N*4     =    160,000 B
  int*   ofs  = (int*)(ws + 36081920);         // (N+1)*4 =    160,004 B (+pad)
  int*   rank = (int*)(ws + 36241936);         // E*4     =  2,560,000 B
  int*   eid  = (int*)(ws + 38801936);         // E*4     =  2,560,000 B
  // total 41,361,936 B

  // zero only the histogram counters
  hipMemsetAsync(cnt, 0, 160000, stream);

  prep_w<<<160, 256, 0, stream>>>(W_msg, W_edge, W_self, WtM, WtE, WtS);
  gemm_rows<8><<<625, 256, 0, stream>>>(x, WtM, b_msg, xm);
  gemm_rows<4><<<625, 256, 0, stream>>>(x, WtS, b_self, xs);
  // CSR build (depends only on dst)
  hist_k<<<2500, 256, 0, stream>>>(dst, cnt, rank);
  scan_k<<<1, 1024, 0, stream>>>(cnt, ofs);
  scatter_k<<<2500, 256, 0, stream>>>(dst, ofs, rank, eid);
  // edge transform + attention logits
  edge_kernel<<<10000, 256, 0, stream>>>(ea, WtE, b_edge, xm, att, src, le_p, alp);
  // gather-based softmax + aggregation + self term, fused (no atomics)
  node_agg<<<10000, 256, 0, stream>>>(le_p, xm, alp, xs, ofs, eid, src, out_p);
}

// Round 2
// 802.572 us; speedup vs baseline: 1.0324x; 1.0143x over previous
//
#include <hip/hip_runtime.h>

#define N_NODES 40000
#define N_EDGES 640000

typedef __attribute__((ext_vector_type(8))) short short8;
typedef __attribute__((ext_vector_type(4))) float float4v;

__device__ inline short f2bf(float f) {
  unsigned u = __float_as_uint(f);
  unsigned r = (u + 0x7FFFu + ((u >> 16) & 1u)) >> 16;
  return (short)r;
}

// ---- convert + transpose weights to bf16: Wt[c][k] = bf16(W[k][c]) ----
__global__ void prep_w(const float* __restrict__ Wm, const float* __restrict__ We,
                       const float* __restrict__ Ws, short* __restrict__ WtM,
                       short* __restrict__ WtE, short* __restrict__ WtS) {
  int i = blockIdx.x * 256 + threadIdx.x;  // 40960 total
  if (i < 16384) {
    int c = i >> 7, k = i & 127;
    WtM[c * 128 + k] = f2bf(Wm[k * 128 + c]);
  } else if (i < 32768) {
    int j = i - 16384;
    int c = j >> 7, k = j & 127;
    WtE[c * 128 + k] = f2bf(We[k * 128 + c]);
  } else {
    int j = i - 32768;
    int c = j >> 7, k = j & 127;  // c in 0..63
    WtS[c * 128 + k] = f2bf(Ws[k * 64 + c]);
  }
}

// ---- generic row-tile GEMM: out[M, NT*16] = A[M,128] @ W[128, NT*16] + bias ----
template <int NT>
__global__ __launch_bounds__(256) void gemm_rows(const float* __restrict__ A,
                                                 const short* __restrict__ Wt,
                                                 const float* __restrict__ bias,
                                                 float* __restrict__ out) {
  __shared__ short wt[NT * 16 * 136];
  for (int i = threadIdx.x; i < NT * 16 * 16; i += 256) {
    int c = i >> 4, j = i & 15;
    *(uint4*)&wt[c * 136 + j * 8] = ((const uint4*)Wt)[i];
  }
  __syncthreads();
  const int l = threadIdx.x & 63, w = threadIdx.x >> 6;
  const int lr = l & 15, q = l >> 4;
  const int row = blockIdx.x * 64 + w * 16 + lr;
  float4v acc[NT];
#pragma unroll
  for (int t = 0; t < NT; ++t) acc[t] = (float4v){0.f, 0.f, 0.f, 0.f};
  const float* ap = A + (size_t)row * 128 + q * 8;
#pragma unroll
  for (int s = 0; s < 4; ++s) {
    float4 a0 = *(const float4*)(ap + s * 32);
    float4 a1 = *(const float4*)(ap + s * 32 + 4);
    short8 af;
    af[0] = f2bf(a0.x); af[1] = f2bf(a0.y); af[2] = f2bf(a0.z); af[3] = f2bf(a0.w);
    af[4] = f2bf(a1.x); af[5] = f2bf(a1.y); af[6] = f2bf(a1.z); af[7] = f2bf(a1.w);
#pragma unroll
    for (int t = 0; t < NT; ++t) {
      short8 bf = *(const short8*)&wt[(t * 16 + lr) * 136 + s * 32 + q * 8];
      acc[t] = __builtin_amdgcn_mfma_f32_16x16x32_bf16(af, bf, acc[t], 0, 0, 0);
    }
  }
  const int orow = blockIdx.x * 64 + w * 16 + q * 4;
#pragma unroll
  for (int t = 0; t < NT; ++t) {
    int col = lr + 16 * t;
    float b = bias[col];
#pragma unroll
    for (int j = 0; j < 4; ++j)
      out[(size_t)(orow + j) * (NT * 16) + col] = acc[t][j] + b;
  }
}

// ---- fused edge kernel: le = ea@W_edge + b_edge (store), m = le + xm[src],
//      alpha[e,h] = leaky_relu(sum_c m[e,h*64+c]*att[h*64+c]) ----
__global__ __launch_bounds__(256) void edge_kernel(
    const float* __restrict__ ea, const short* __restrict__ WtE,
    const float* __restrict__ b_edge, const float* __restrict__ xm,
    const float* __restrict__ att, const int* __restrict__ src,
    float* __restrict__ le_out, float* __restrict__ alpha_out) {
  __shared__ short wt[128 * 136];
  __shared__ int sid[64];
  for (int i = threadIdx.x; i < 128 * 16; i += 256) {
    int c = i >> 4, j = i & 15;
    *(uint4*)&wt[c * 136 + j * 8] = ((const uint4*)WtE)[i];
  }
  if (threadIdx.x < 64) sid[threadIdx.x] = src[blockIdx.x * 64 + threadIdx.x];
  __syncthreads();
  const int l = threadIdx.x & 63, w = threadIdx.x >> 6;
  const int lr = l & 15, q = l >> 4;
  const int r0 = blockIdx.x * 64 + w * 16;
  float4v acc[8];
#pragma unroll
  for (int t = 0; t < 8; ++t) acc[t] = (float4v){0.f, 0.f, 0.f, 0.f};
  const float* ap = ea + (size_t)(r0 + lr) * 128 + q * 8;
#pragma unroll
  for (int s = 0; s < 4; ++s) {
    float4 a0 = *(const float4*)(ap + s * 32);
    float4 a1 = *(const float4*)(ap + s * 32 + 4);
    short8 af;
    af[0] = f2bf(a0.x); af[1] = f2bf(a0.y); af[2] = f2bf(a0.z); af[3] = f2bf(a0.w);
    af[4] = f2bf(a1.x); af[5] = f2bf(a1.y); af[6] = f2bf(a1.z); af[7] = f2bf(a1.w);
#pragma unroll
    for (int t = 0; t < 8; ++t) {
      short8 bf = *(const short8*)&wt[(t * 16 + lr) * 136 + s * 32 + q * 8];
      acc[t] = __builtin_amdgcn_mfma_f32_16x16x32_bf16(af, bf, acc[t], 0, 0, 0);
    }
  }
  const int rb = q * 4;
  int sidr[4];
#pragma unroll
  for (int j = 0; j < 4; ++j) sidr[j] = sid[w * 16 + rb + j];
  float p[8];
#pragma unroll
  for (int k = 0; k < 8; ++k) p[k] = 0.f;
#pragma unroll
  for (int t = 0; t < 8; ++t) {
    int col = lr + 16 * t;
    float b = b_edge[col];
    float av = att[col];
    int hp = (t >> 2) * 4;  // head = col>>6 = t>>2
#pragma unroll
    for (int j = 0; j < 4; ++j) {
      float lev = acc[t][j] + b;
      le_out[(size_t)(r0 + rb + j) * 128 + col] = lev;
      float mv = lev + xm[(size_t)sidr[j] * 128 + col];
      p[hp + j] += mv * av;
    }
  }
  // butterfly-reduce over the 16 lanes of each quad group
#pragma unroll
  for (int d = 1; d < 16; d <<= 1) {
#pragma unroll
    for (int k = 0; k < 8; ++k) p[k] += __shfl_xor(p[k], d);
  }
  if (lr < 8) {
    int j = lr >> 1, h = lr & 1;
    float v = p[h * 4 + j];
    alpha_out[(size_t)(r0 + rb + j) * 2 + h] = v > 0.f ? v : 0.2f * v;
  }
}

// ==================== CSR build (by destination) ====================

__global__ void hist_k(const int* __restrict__ dst, int* __restrict__ cnt,
                       int* __restrict__ rank) {
  int e = blockIdx.x * 256 + threadIdx.x;  // E exact
  rank[e] = atomicAdd(&cnt[dst[e]], 1);
}

// single-block exclusive scan of cnt[0..N) -> ofs[0..N]
__global__ __launch_bounds__(1024) void scan_k(const int* __restrict__ cnt,
                                               int* __restrict__ ofs) {
  __shared__ int tsum[1024];
  const int t = threadIdx.x;
  const int b = t * 40;                       // 1024*40 = 40960 >= 40000
  const int hi = min(b + 40, N_NODES);
  int s = 0;
  for (int i = b; i < hi; ++i) s += cnt[i];
  tsum[t] = s;
  __syncthreads();
  for (int d = 1; d < 1024; d <<= 1) {
    int v = (t >= d) ? tsum[t - d] : 0;
    __syncthreads();
    tsum[t] += v;
    __syncthreads();
  }
  int run = (t == 0) ? 0 : tsum[t - 1];       // exclusive base for this chunk
  for (int i = b; i < hi; ++i) { ofs[i] = run; run += cnt[i]; }
  if (t == 1023) ofs[N_NODES] = run;          // grand total (chunks >=1000 empty)
}

__global__ void scatter_k(const int* __restrict__ dst, const int* __restrict__ ofs,
                          const int* __restrict__ rank, int* __restrict__ eid) {
  int e = blockIdx.x * 256 + threadIdx.x;  // E exact
  eid[ofs[dst[e]] + rank[e]] = e;
}

// ==================== per-node softmax + aggregation (no atomics) ====================
// one wave per node; lane l owns channel l of both heads (cols l and 64+l).
// Softmax computed WITHOUT max-shift (shift-invariant; logits are O(10), safe in f32).
__global__ __launch_bounds__(256) void node_agg(
    const float* __restrict__ le, const float* __restrict__ xm,
    const float* __restrict__ alp, const float* __restrict__ xs,
    const int* __restrict__ ofs, const int* __restrict__ eid,
    const int* __restrict__ src, float* __restrict__ out) {
  const int w = threadIdx.x >> 6, l = threadIdx.x & 63;
  const int n = blockIdx.x * 4 + w;  // grid 10000 -> 40000 nodes exact
  const int beg = ofs[n];
  const int deg = ofs[n + 1] - beg;
  float acc = 0.f;
  if (deg > 0) {
    // denom pass; first-chunk per-lane regs (edge id, src, exp) kept for reuse
    int eR = 0, sR = 0;
    float w0R = 0.f, w1R = 0.f;
    float s0 = 0.f, s1 = 0.f;
    if (l < deg) {
      eR = eid[beg + l];
      sR = src[eR];
      w0R = __expf(alp[2 * eR]);
      w1R = __expf(alp[2 * eR + 1]);
      s0 = w0R; s1 = w1R;
    }
    for (int i = l + 64; i < deg; i += 64) {
      int e = eid[beg + i];
      s0 += __expf(alp[2 * e]);
      s1 += __expf(alp[2 * e + 1]);
    }
#pragma unroll
    for (int d = 1; d < 64; d <<= 1) {
      s0 += __shfl_xor(s0, d);
      s1 += __shfl_xor(s1, d);
    }
    const float r0 = 1.f / (s0 + 1e-16f);
    const float r1 = 1.f / (s1 + 1e-16f);
    w0R *= r0; w1R *= r1;
    // aggregation: 64-edge chunks; 8-deep batched gathers for MLP
    for (int base = 0; base < deg; base += 64) {
      if (base > 0) {  // recompute chunk regs (deg > 64 is rare)
        int i = base + l;
        eR = 0; sR = 0; w0R = 0.f; w1R = 0.f;
        if (i < deg) {
          eR = eid[beg + i];
          sR = src[eR];
          w0R = __expf(alp[2 * eR]) * r0;
          w1R = __expf(alp[2 * eR + 1]) * r1;
        }
      }
      const int c = min(64, deg - base);
      if (c == 64) {
#pragma unroll 1
        for (int jj = 0; jj < 64; jj += 8) {
          int e8[8], s8[8];
          float w08[8], w18[8];
#pragma unroll
          for (int k = 0; k < 8; ++k) {
            e8[k] = __shfl(eR, jj + k);
            s8[k] = __shfl(sR, jj + k);
            w08[k] = __shfl(w0R, jj + k);
            w18[k] = __shfl(w1R, jj + k);
          }
          float v0[8], v1[8], x0[8], x1[8];
#pragma unroll
          for (int k = 0; k < 8; ++k) {
            const float* lp = le + (size_t)e8[k] * 128;
            const float* xp = xm + (size_t)s8[k] * 128;
            v0[k] = lp[l]; v1[k] = lp[64 + l];
            x0[k] = xp[l]; x1[k] = xp[64 + l];
          }
#pragma unroll
          for (int k = 0; k < 8; ++k)
            acc += w08[k] * (v0[k] + x0[k]) + w18[k] * (v1[k] + x1[k]);
        }
      } else {
        // tail: batch 4-deep
        int j = 0;
        for (; j + 4 <= c; j += 4) {
          int e4[4], s4[4];
          float w04[4], w14[4];
#pragma unroll
          for (int k = 0; k < 4; ++k) {
            e4[k] = __shfl(eR, j + k);
            s4[k] = __shfl(sR, j + k);
            w04[k] = __shfl(w0R, j + k);
            w14[k] = __shfl(w1R, j + k);
          }
          float v0[4], v1[4], x0[4], x1[4];
#pragma unroll
          for (int k = 0; k < 4; ++k) {
            const float* lp = le + (size_t)e4[k] * 128;
            const float* xp = xm + (size_t)s4[k] * 128;
            v0[k] = lp[l]; v1[k] = lp[64 + l];
            x0[k] = xp[l]; x1[k] = xp[64 + l];
          }
#pragma unroll
          for (int k = 0; k < 4; ++k)
            acc += w04[k] * (v0[k] + x0[k]) + w14[k] * (v1[k] + x1[k]);
        }
        for (; j < c; ++j) {
          int e = __shfl(eR, j), s = __shfl(sR, j);
          float w0 = __shfl(w0R, j), w1 = __shfl(w1R, j);
          acc += w0 * (le[(size_t)e * 128 + l] + xm[(size_t)s * 128 + l]) +
                 w1 * (le[(size_t)e * 128 + 64 + l] + xm[(size_t)s * 128 + 64 + l]);
        }
      }
    }
  }
  out[(size_t)n * 64 + l] = 0.5f * acc + xs[(size_t)n * 64 + l];
}

extern "C" void kernel_launch(void* const* d_in, const int* in_sizes, int n_in,
                              void* d_out, int out_size, void* d_ws, size_t ws_size,
                              hipStream_t stream) {
  const float* x      = (const float*)d_in[0];
  const float* ea     = (const float*)d_in[1];
  const float* W_msg  = (const float*)d_in[2];
  const float* b_msg  = (const float*)d_in[3];
  const float* W_edge = (const float*)d_in[4];
  const float* b_edge = (const float*)d_in[5];
  const float* W_self = (const float*)d_in[6];
  const float* b_self = (const float*)d_in[7];
  const float* att    = (const float*)d_in[8];
  const int*   eidx   = (const int*)d_in[9];
  const int* src = eidx;
  const int* dst = eidx + N_EDGES;
  float* out_p = (float*)d_out;
  float* le_p  = out_p + (size_t)N_NODES * 64;

  char* ws = (char*)d_ws;
  short* WtM  = (short*)(ws);                  // 32768 B
  short* WtE  = (short*)(ws + 32768);          // 32768 B
  short* WtS  = (short*)(ws + 65536);          // 16384 B
  float* xm   = (float*)(ws + 81920);          // N*128*4 = 20,480,000 B
  float* xs   = (float*)(ws + 20561920);       // N*64*4  = 10,240,000 B
  float* alp  = (float*)(ws + 30801920);       // E*2*4   =  5,120,000 B
  int*   cnt  = (int*)(ws + 35921920);         // N*4     =    160,000 B
  int*   ofs  = (int*)(ws + 36081920);         // (N+1)*4 =    160,004 B (+pad)
  int*   rank = (int*)(ws + 36241936);         // E*4     =  2,560,000 B
  int*   eid  = (int*)(ws + 38801936);         // E*4     =  2,560,000 B
  // total 41,361,936 B

  // zero only the histogram counters
  hipMemsetAsync(cnt, 0, 160000, stream);

  prep_w<<<160, 256, 0, stream>>>(W_msg, W_edge, W_self, WtM, WtE, WtS);
  gemm_rows<8><<<625, 256, 0, stream>>>(x, WtM, b_msg, xm);
  gemm_rows<4><<<625, 256, 0, stream>>>(x, WtS, b_self, xs);
  // CSR build (depends only on dst)
  hist_k<<<2500, 256, 0, stream>>>(dst, cnt, rank);
  scan_k<<<1, 1024, 0, stream>>>(cnt, ofs);
  scatter_k<<<2500, 256, 0, stream>>>(dst, ofs, rank, eid);
  // edge transform + attention logits
  edge_kernel<<<10000, 256, 0, stream>>>(ea, WtE, b_edge, xm, att, src, le_p, alp);
  // gather-based softmax + aggregation + self term, fused (no atomics)
  node_agg<<<10000, 256, 0, stream>>>(le_p, xm, alp, xs, ofs, eid, src, out_p);
}